// Round 1
// baseline (210.771 us; speedup 1.0000x reference)
//
#include <hip/hip_runtime.h>
#include <math.h>

#define BB 4096
#define MM 100
#define EE 128
#define RR 64
#define PITCH 129   // +1 pad: bank = (m + e) % 32 -> conflict-free in both phases

// ---- tiny kernel: wsum vectors (E,) for both attention modules ----
__global__ void wsum_kernel(const float* __restrict__ ua_key,
                            const float* __restrict__ ua_val,
                            const float* __restrict__ ia_key,
                            const float* __restrict__ ia_val,
                            float* __restrict__ ws) {
    int e = threadIdx.x;  // 128 threads
    float wa = 0.f, wi = 0.f;
    #pragma unroll
    for (int r = 0; r < RR; ++r) {
        wa += ua_key[r * EE + e] * ua_val[r * EE + e];
        wi += ia_key[r * EE + e] * ia_val[r * EE + e];
    }
    ws[e]      = wa;
    ws[EE + e] = wi;
}

// load one embedding row (128 f32), maxnorm-normalize, store to LDS. One wave.
__device__ __forceinline__ void load_norm_row(const float* __restrict__ src,
                                              float* __restrict__ dst, int lane) {
    float2 v = *reinterpret_cast<const float2*>(src + 2 * lane);
    float ss = v.x * v.x + v.y * v.y;
    #pragma unroll
    for (int off = 32; off; off >>= 1) ss += __shfl_xor(ss, off, 64);
    float n = sqrtf(ss);
    float scale = (n > 1.0f) ? (1.0f / (n + 1e-7f)) : 1.0f;
    dst[2 * lane]     = v.x * scale;
    dst[2 * lane + 1] = v.y * scale;
}

__global__ __launch_bounds__(256)
void hlrm_main(const int* __restrict__ user_id,
               const int* __restrict__ ip_id,
               const int* __restrict__ in_id,
               const int* __restrict__ inter_id,
               const float* __restrict__ user_w,
               const float* __restrict__ item_w,
               const float* __restrict__ ws,
               float* __restrict__ out) {
    __shared__ float s_inter[MM * PITCH];   // 51,600 B (normalized inter tile)
    __shared__ float s_u[EE], s_ip[EE], s_in[EE];
    __shared__ float s_q[4][EE];
    __shared__ float s_a[4][MM];            // logits, then softmax weights
    __shared__ float s_S[4][EE];            // attention-weighted inter sums

    const int b    = blockIdx.x;
    const int tid  = threadIdx.x;
    const int lane = tid & 63;
    const int wave = tid >> 6;

    // ---- Phase A: gather + maxnorm-normalize u / ip / inn / inter into LDS ----
    if (wave == 0) {
        load_norm_row(user_w + (size_t)user_id[b] * EE, s_u, lane);
    } else if (wave == 1) {
        load_norm_row(item_w + (size_t)ip_id[b] * EE, s_ip, lane);
    } else if (wave == 2) {
        load_norm_row(item_w + (size_t)in_id[b] * EE, s_in, lane);
    }
    for (int m = wave; m < MM; m += 4) {
        int id = inter_id[b * MM + m];
        load_norm_row(item_w + (size_t)id * EE, &s_inter[m * PITCH], lane);
    }
    __syncthreads();

    // ---- Phase Q: per-element q vectors; also emit u/ip/inn outputs ----
    if (tid < EE) {
        int e = tid;
        float u = s_u[e], ip = s_ip[e], inn = s_in[e];
        float wa = ws[e], wi = ws[EE + e];
        s_q[0][e] = u * ip * wa;
        s_q[1][e] = u * ip * wi;
        s_q[2][e] = u * inn * wa;
        s_q[3][e] = u * inn * wi;
        size_t base = (size_t)b * EE + e;
        out[0 * (size_t)BB * EE + base] = u;
        out[1 * (size_t)BB * EE + base] = ip;
        out[2 * (size_t)BB * EE + base] = inn;
    }
    __syncthreads();

    // ---- Phase B: logits[k][m] = dot(interN[m], q_k) ----
    if (tid < MM) {
        int m = tid;
        const float* row = &s_inter[m * PITCH];
        float a0 = 0.f, a1 = 0.f, a2 = 0.f, a3 = 0.f;
        #pragma unroll 8
        for (int e = 0; e < EE; ++e) {
            float x = row[e];                  // bank (m+e)%32: conflict-free
            a0 += x * s_q[0][e];               // broadcast reads
            a1 += x * s_q[1][e];
            a2 += x * s_q[2][e];
            a3 += x * s_q[3][e];
        }
        s_a[0][m] = a0; s_a[1][m] = a1; s_a[2][m] = a2; s_a[3][m] = a3;
    }
    __syncthreads();

    // ---- Phase SM: softmax over m, one attention per wave ----
    {
        int k = wave;
        float l0 = (lane < MM)      ? s_a[k][lane]      : -INFINITY;
        float l1 = (lane + 64 < MM) ? s_a[k][lane + 64] : -INFINITY;
        float mx = fmaxf(l0, l1);
        #pragma unroll
        for (int off = 32; off; off >>= 1) mx = fmaxf(mx, __shfl_xor(mx, off, 64));
        float e0 = (lane < MM)      ? expf(l0 - mx) : 0.f;
        float e1 = (lane + 64 < MM) ? expf(l1 - mx) : 0.f;
        float s = e0 + e1;
        #pragma unroll
        for (int off = 32; off; off >>= 1) s += __shfl_xor(s, off, 64);
        float inv = 1.0f / s;
        if (lane < MM)      s_a[k][lane]      = e0 * inv;
        if (lane + 64 < MM) s_a[k][lane + 64] = e1 * inv;
    }
    __syncthreads();

    // ---- Phase C: S_k[e] = sum_m a_k[m] * interN[m][e] (2 k's per thread) ----
    {
        int e  = tid & 127;
        int kb = tid >> 7;   // 0 or 1; thread handles k = kb and kb+2
        float sA = 0.f, sB = 0.f;
        #pragma unroll 4
        for (int m = 0; m < MM; ++m) {
            float x = s_inter[m * PITCH + e];  // consecutive banks across lanes
            sA += s_a[kb][m] * x;              // broadcast
            sB += s_a[kb + 2][m] * x;
        }
        s_S[kb][e]     = sA;
        s_S[kb + 2][e] = sB;
    }
    __syncthreads();

    // ---- Epilogue: rel_p / rel_n ----
    if (tid < EE) {
        int e = tid;
        float u = s_u[e], ip = s_ip[e], inn = s_in[e];
        float wa = ws[e], wi = ws[EE + e];
        float relp = ip * wa * s_S[0][e] + u * wi * s_S[1][e];
        float reln = inn * wa * s_S[2][e] + u * wi * s_S[3][e];
        size_t base = (size_t)b * EE + e;
        out[3 * (size_t)BB * EE + base] = relp;
        out[4 * (size_t)BB * EE + base] = reln;
    }
}

extern "C" void kernel_launch(void* const* d_in, const int* in_sizes, int n_in,
                              void* d_out, int out_size, void* d_ws, size_t ws_size,
                              hipStream_t stream) {
    const int*   user_id   = (const int*)d_in[0];
    const int*   item_id_p = (const int*)d_in[1];
    const int*   item_id_n = (const int*)d_in[2];
    const int*   inter_id  = (const int*)d_in[3];
    const float* user_w    = (const float*)d_in[4];
    const float* item_w    = (const float*)d_in[5];
    const float* ua_key    = (const float*)d_in[6];
    const float* ua_val    = (const float*)d_in[7];
    const float* ia_key    = (const float*)d_in[8];
    const float* ia_val    = (const float*)d_in[9];
    float* out = (float*)d_out;
    float* ws  = (float*)d_ws;   // [0:128) = wsum_ua, [128:256) = wsum_ia

    wsum_kernel<<<1, 128, 0, stream>>>(ua_key, ua_val, ia_key, ia_val, ws);
    hlrm_main<<<BB, 256, 0, stream>>>(user_id, item_id_p, item_id_n, inter_id,
                                      user_w, item_w, ws, out);
}

// Round 2
// 74.307 us; speedup vs baseline: 2.8365x; 2.8365x over previous
//
#include <hip/hip_runtime.h>
#include <math.h>

#define BB 4096
#define MM 100
#define EE 128
#define RR 64

__device__ __forceinline__ float4 ld4(const float* p) {
    return *reinterpret_cast<const float4*>(p);
}
__device__ __forceinline__ float f4dot(float4 a, float4 b) {
    return a.x * b.x + a.y * b.y + a.z * b.z + a.w * b.w;
}
__device__ __forceinline__ float4 f4mul3(float4 a, float4 b, float4 c) {
    float4 r;
    r.x = a.x * b.x * c.x; r.y = a.y * b.y * c.y;
    r.z = a.z * b.z * c.z; r.w = a.w * b.w * c.w;
    return r;
}
__device__ __forceinline__ float4 f4fma(float4 v, float s, float4 acc) {
    acc.x += v.x * s; acc.y += v.y * s; acc.z += v.z * s; acc.w += v.w * s;
    return acc;
}
__device__ __forceinline__ float4 f4xor32(float4 a) {
    a.x += __shfl_xor(a.x, 32, 64); a.y += __shfl_xor(a.y, 32, 64);
    a.z += __shfl_xor(a.z, 32, 64); a.w += __shfl_xor(a.w, 32, 64);
    return a;
}

// ---- ws vectors: block 0 -> sum(ua_key*ua_val) over R; block 1 -> ia ----
__global__ __launch_bounds__(512)
void wsum_kernel(const float* __restrict__ ua_key, const float* __restrict__ ua_val,
                 const float* __restrict__ ia_key, const float* __restrict__ ia_val,
                 float* __restrict__ ws) {
    __shared__ float part[4][EE];
    const float* k = (blockIdx.x == 0) ? ua_key : ia_key;
    const float* v = (blockIdx.x == 0) ? ua_val : ia_val;
    int e = threadIdx.x & 127;
    int q = threadIdx.x >> 7;               // 0..3, 16 r's each
    float s = 0.f;
    #pragma unroll
    for (int j = 0; j < 16; ++j) {
        int r = q * 16 + j;
        s += k[r * EE + e] * v[r * EE + e];
    }
    part[q][e] = s;
    __syncthreads();
    if (threadIdx.x < EE)
        ws[blockIdx.x * EE + e] = part[0][e] + part[1][e] + part[2][e] + part[3][e];
}

__global__ __launch_bounds__(256)
void hlrm_main(const int* __restrict__ user_id,
               const int* __restrict__ ip_id,
               const int* __restrict__ in_id,
               const int* __restrict__ inter_id,
               const float* __restrict__ user_w,
               const float* __restrict__ item_w,
               const float* __restrict__ ws,
               float* __restrict__ out) {
    __shared__ float s_u[EE], s_ip[EE], s_in[EE];
    __shared__ float s_part[4][4][EE];
    __shared__ float s_den[4][4];

    const int b    = blockIdx.x;
    const int tid  = threadIdx.x;
    const int lane = tid & 63;
    const int wave = tid >> 6;
    const int half = lane >> 5;   // 0/1: which row of the pair this half owns
    const int hl   = lane & 31;   // lane within half: owns e = hl*4 .. hl*4+3

    // ---- Phase 0: gather + normalize u / ip / inn (3 rows on waves 0-1) ----
    if (wave == 0 || (wave == 1 && half == 0)) {
        const float* src; int id; float* dst;
        if (wave == 0 && half == 0)      { id = user_id[b]; src = user_w; dst = s_u;  }
        else if (wave == 0)              { id = ip_id[b];   src = item_w; dst = s_ip; }
        else                             { id = in_id[b];   src = item_w; dst = s_in; }
        float4 v = ld4(src + (size_t)id * EE + hl * 4);
        float ss = f4dot(v, v);
        #pragma unroll
        for (int off = 1; off < 32; off <<= 1) ss += __shfl_xor(ss, off, 64);
        float n  = sqrtf(ss);
        float sc = (n > 1.f) ? 1.f / (n + 1e-7f) : 1.f;
        float4 o; o.x = v.x * sc; o.y = v.y * sc; o.z = v.z * sc; o.w = v.w * sc;
        *reinterpret_cast<float4*>(dst + hl * 4) = o;
    }

    // preload this wave's inter ids: lane 2i+h holds id for pair p=wave+4i, row 2p+h
    int idreg = 0;
    {
        int p = wave + 4 * (lane >> 1);
        if (lane < 26 && p < 50) idreg = inter_id[b * MM + 2 * p + (lane & 1)];
    }
    __syncthreads();

    // ---- per-lane q vectors (4 e-elements each) ----
    float4 u4  = ld4(s_u  + hl * 4);
    float4 p4  = ld4(s_ip + hl * 4);
    float4 n4  = ld4(s_in + hl * 4);
    float4 wa4 = ld4(ws + hl * 4);
    float4 wi4 = ld4(ws + EE + hl * 4);
    float4 up  = f4mul3(u4, p4, wa4);   // q0: UA pos  (u*ip*wa)
    float4 q1  = f4mul3(u4, p4, wi4);   // q1: IA pos  (u*ip*wi)
    float4 q2  = f4mul3(u4, n4, wa4);   // q2: UA neg  (u*inn*wa)
    float4 q3  = f4mul3(u4, n4, wi4);   // q3: IA neg  (u*inn*wi)
    float4 q0  = up;

    // ---- main loop: each wave-half streams one inter row per iteration ----
    float4 S0 = {0,0,0,0}, S1 = {0,0,0,0}, S2 = {0,0,0,0}, S3 = {0,0,0,0};
    float den0 = 0.f, den1 = 0.f, den2 = 0.f, den3 = 0.f;

    const int niter = (wave < 2) ? 13 : 12;   // pairs p = wave + 4*i < 50
    int id0 = __shfl(idreg, half);
    float4 v = ld4(item_w + (size_t)id0 * EE + hl * 4);

    for (int i = 0; i < niter; ++i) {
        float4 vn = v;
        if (i + 1 < niter) {
            int idn = __shfl(idreg, 2 * (i + 1) + half);
            vn = ld4(item_w + (size_t)idn * EE + hl * 4);
        }
        float ss = f4dot(v, v);
        float d0 = f4dot(v, q0), d1 = f4dot(v, q1);
        float d2 = f4dot(v, q2), d3 = f4dot(v, q3);
        #pragma unroll
        for (int off = 1; off < 32; off <<= 1) {
            ss += __shfl_xor(ss, off, 64);
            d0 += __shfl_xor(d0, off, 64);
            d1 += __shfl_xor(d1, off, 64);
            d2 += __shfl_xor(d2, off, 64);
            d3 += __shfl_xor(d3, off, 64);
        }
        float n  = sqrtf(ss);
        float sc = (n > 1.f) ? 1.f / (n + 1e-7f) : 1.f;
        // logits are O(1) here (all factors maxnorm'd) -> exp never overflows,
        // so softmax needs no max subtraction: accumulate unnormalized.
        float w0 = __expf(d0 * sc), w1 = __expf(d1 * sc);
        float w2 = __expf(d2 * sc), w3 = __expf(d3 * sc);
        den0 += w0; den1 += w1; den2 += w2; den3 += w3;
        S0 = f4fma(v, w0 * sc, S0);
        S1 = f4fma(v, w1 * sc, S1);
        S2 = f4fma(v, w2 * sc, S2);
        S3 = f4fma(v, w3 * sc, S3);
        v = vn;
    }

    // combine the two halves of the wave (same e-slice, different rows)
    S0 = f4xor32(S0); S1 = f4xor32(S1); S2 = f4xor32(S2); S3 = f4xor32(S3);
    den0 += __shfl_xor(den0, 32, 64);
    den1 += __shfl_xor(den1, 32, 64);
    den2 += __shfl_xor(den2, 32, 64);
    den3 += __shfl_xor(den3, 32, 64);

    if (half == 0) {
        *reinterpret_cast<float4*>(&s_part[wave][0][hl * 4]) = S0;
        *reinterpret_cast<float4*>(&s_part[wave][1][hl * 4]) = S1;
        *reinterpret_cast<float4*>(&s_part[wave][2][hl * 4]) = S2;
        *reinterpret_cast<float4*>(&s_part[wave][3][hl * 4]) = S3;
        if (hl == 0) {
            s_den[wave][0] = den0; s_den[wave][1] = den1;
            s_den[wave][2] = den2; s_den[wave][3] = den3;
        }
    }
    __syncthreads();

    // ---- final: cross-wave reduce + epilogue + all 5 outputs ----
    if (tid < EE) {
        int e = tid;
        float D0 = s_den[0][0] + s_den[1][0] + s_den[2][0] + s_den[3][0];
        float D1 = s_den[0][1] + s_den[1][1] + s_den[2][1] + s_den[3][1];
        float D2 = s_den[0][2] + s_den[1][2] + s_den[2][2] + s_den[3][2];
        float D3 = s_den[0][3] + s_den[1][3] + s_den[2][3] + s_den[3][3];
        float S0e = (s_part[0][0][e] + s_part[1][0][e] + s_part[2][0][e] + s_part[3][0][e]) / D0;
        float S1e = (s_part[0][1][e] + s_part[1][1][e] + s_part[2][1][e] + s_part[3][1][e]) / D1;
        float S2e = (s_part[0][2][e] + s_part[1][2][e] + s_part[2][2][e] + s_part[3][2][e]) / D2;
        float S3e = (s_part[0][3][e] + s_part[1][3][e] + s_part[2][3][e] + s_part[3][3][e]) / D3;
        float u = s_u[e], ip = s_ip[e], inn = s_in[e];
        float wae = ws[e], wie = ws[EE + e];
        float relp = ip  * wae * S0e + u * wie * S1e;
        float reln = inn * wae * S2e + u * wie * S3e;
        size_t base = (size_t)b * EE + e;
        out[0 * (size_t)BB * EE + base] = u;
        out[1 * (size_t)BB * EE + base] = ip;
        out[2 * (size_t)BB * EE + base] = inn;
        out[3 * (size_t)BB * EE + base] = relp;
        out[4 * (size_t)BB * EE + base] = reln;
    }
}

extern "C" void kernel_launch(void* const* d_in, const int* in_sizes, int n_in,
                              void* d_out, int out_size, void* d_ws, size_t ws_size,
                              hipStream_t stream) {
    const int*   user_id   = (const int*)d_in[0];
    const int*   item_id_p = (const int*)d_in[1];
    const int*   item_id_n = (const int*)d_in[2];
    const int*   inter_id  = (const int*)d_in[3];
    const float* user_w    = (const float*)d_in[4];
    const float* item_w    = (const float*)d_in[5];
    const float* ua_key    = (const float*)d_in[6];
    const float* ua_val    = (const float*)d_in[7];
    const float* ia_key    = (const float*)d_in[8];
    const float* ia_val    = (const float*)d_in[9];
    float* out = (float*)d_out;
    float* ws  = (float*)d_ws;   // [0:128)=wsum_ua, [128:256)=wsum_ia

    wsum_kernel<<<2, 512, 0, stream>>>(ua_key, ua_val, ia_key, ia_val, ws);
    hlrm_main<<<BB, 256, 0, stream>>>(user_id, item_id_p, item_id_n, inter_id,
                                      user_w, item_w, ws, out);
}

// Round 3
// 63.569 us; speedup vs baseline: 3.3156x; 1.1689x over previous
//
#include <hip/hip_runtime.h>
#include <math.h>

#define BB 4096
#define MM 100
#define EE 128
#define RR 64

__device__ __forceinline__ float4 ld4(const float* p) {
    return *reinterpret_cast<const float4*>(p);
}
__device__ __forceinline__ void st4(float* p, float4 v) {
    *reinterpret_cast<float4*>(p) = v;
}
__device__ __forceinline__ float f4dot(float4 a, float4 b) {
    return a.x * b.x + a.y * b.y + a.z * b.z + a.w * b.w;
}
__device__ __forceinline__ float4 f4mul3(float4 a, float4 b, float4 c) {
    float4 r;
    r.x = a.x * b.x * c.x; r.y = a.y * b.y * c.y;
    r.z = a.z * b.z * c.z; r.w = a.w * b.w * c.w;
    return r;
}
__device__ __forceinline__ float4 f4fma(float4 v, float s, float4 acc) {
    acc.x += v.x * s; acc.y += v.y * s; acc.z += v.z * s; acc.w += v.w * s;
    return acc;
}
__device__ __forceinline__ float4 f4red(float4 a, int off) {
    a.x += __shfl_xor(a.x, off, 64); a.y += __shfl_xor(a.y, off, 64);
    a.z += __shfl_xor(a.z, off, 64); a.w += __shfl_xor(a.w, off, 64);
    return a;
}

// ---- ws vectors: block 0 -> sum(ua_key*ua_val) over R; block 1 -> ia ----
__global__ __launch_bounds__(512)
void wsum_kernel(const float* __restrict__ ua_key, const float* __restrict__ ua_val,
                 const float* __restrict__ ia_key, const float* __restrict__ ia_val,
                 float* __restrict__ ws) {
    __shared__ float part[4][EE];
    const float* k = (blockIdx.x == 0) ? ua_key : ia_key;
    const float* v = (blockIdx.x == 0) ? ua_val : ia_val;
    int e = threadIdx.x & 127;
    int q = threadIdx.x >> 7;
    float s = 0.f;
    #pragma unroll
    for (int j = 0; j < 16; ++j) {
        int r = q * 16 + j;
        s += k[r * EE + e] * v[r * EE + e];
    }
    part[q][e] = s;
    __syncthreads();
    if (threadIdx.x < EE)
        ws[blockIdx.x * EE + e] = part[0][e] + part[1][e] + part[2][e] + part[3][e];
}

__global__ __launch_bounds__(256)
void hlrm_main(const int* __restrict__ user_id,
               const int* __restrict__ ip_id,
               const int* __restrict__ in_id,
               const int* __restrict__ inter_id,
               const float* __restrict__ user_w,
               const float* __restrict__ item_w,
               const float* __restrict__ ws,
               float* __restrict__ out) {
    __shared__ float s_u[EE], s_ip[EE], s_in[EE];
    __shared__ float s_part[4][4][EE];   // [wave][k][e]
    __shared__ float s_den[4][4];

    const int b    = blockIdx.x;
    const int tid  = threadIdx.x;
    const int lane = tid & 63;
    const int wave = tid >> 6;
    const int g    = lane >> 4;   // 16-lane group: owns one row per iteration
    const int hl   = lane & 15;   // lane-in-group: owns elems e0..e0+3, e1..e1+3
    const int wg   = wave * 4 + g;
    const int e0   = hl * 4;
    const int e1   = 64 + hl * 4;

    // preload inter ids: lane j (<28) holds id for row (j>>2)*16 + wave*4 + (j&3)
    int idreg = 0;
    if (lane < 28) {
        int row = (lane >> 2) * 16 + wave * 4 + (lane & 3);
        if (row < MM) idreg = inter_id[b * MM + row];
    }

    // ---- stage u / ip / inn normalized into LDS (3 x 32-lane halves) ----
    if (wave == 0 || (wave == 1 && lane < 32)) {
        const int half32 = lane >> 5, l32 = lane & 31;
        const float* src; int id; float* dst;
        if (wave == 0 && half32 == 0) { id = user_id[b]; src = user_w; dst = s_u;  }
        else if (wave == 0)           { id = ip_id[b];   src = item_w; dst = s_ip; }
        else                          { id = in_id[b];   src = item_w; dst = s_in; }
        float4 v = ld4(src + (size_t)id * EE + l32 * 4);
        float ss = f4dot(v, v);
        #pragma unroll
        for (int off = 1; off < 32; off <<= 1) ss += __shfl_xor(ss, off, 64);
        float n  = sqrtf(ss);
        float sc = (n > 1.f) ? 1.f / (n + 1e-7f) : 1.f;
        float4 o; o.x = v.x * sc; o.y = v.y * sc; o.z = v.z * sc; o.w = v.w * sc;
        st4(dst + l32 * 4, o);
    }

    // prefetch iteration-0 row for this group (row = wg)
    int id0 = __shfl(idreg, g);
    {
        // issue early; uses only idreg
    }
    uint o0 = (uint)id0 * EE;
    float4 va = ld4(item_w + o0 + e0);
    float4 vb = ld4(item_w + o0 + e1);

    __syncthreads();

    // ---- per-lane q fragments (4 attention queries x 8 elems) ----
    float4 ua  = ld4(s_u + e0),  ub  = ld4(s_u + e1);
    float4 pa  = ld4(s_ip + e0), pb  = ld4(s_ip + e1);
    float4 ia  = ld4(s_in + e0), ib  = ld4(s_in + e1);
    float4 waa = ld4(ws + e0),   wab = ld4(ws + e1);
    float4 wia = ld4(ws + EE + e0), wib = ld4(ws + EE + e1);
    float4 qa0 = f4mul3(ua, pa, waa), qb0 = f4mul3(ub, pb, wab);
    float4 qa1 = f4mul3(ua, pa, wia), qb1 = f4mul3(ub, pb, wib);
    float4 qa2 = f4mul3(ua, ia, waa), qb2 = f4mul3(ub, ib, wab);
    float4 qa3 = f4mul3(ua, ia, wia), qb3 = f4mul3(ub, ib, wib);

    // emit u/ip/inn now so the stores overlap the main loop
    if (tid < EE) {
        size_t base = (size_t)b * EE + tid;
        out[0 * (size_t)BB * EE + base] = s_u[tid];
        out[1 * (size_t)BB * EE + base] = s_ip[tid];
        out[2 * (size_t)BB * EE + base] = s_in[tid];
    }

    float4 Sa0 = {0,0,0,0}, Sa1 = {0,0,0,0}, Sa2 = {0,0,0,0}, Sa3 = {0,0,0,0};
    float4 Sb0 = {0,0,0,0}, Sb1 = {0,0,0,0}, Sb2 = {0,0,0,0}, Sb3 = {0,0,0,0};
    float den0 = 0.f, den1 = 0.f, den2 = 0.f, den3 = 0.f;

    // ---- main loop: 7 iterations x 16 rows (4 per wave), rows >=100 masked ----
    #pragma unroll
    for (int i = 0; i < 7; ++i) {
        float4 nva = va, nvb = vb;
        if (i < 6) {
            int idn = __shfl(idreg, (i + 1) * 4 + g);
            uint o = (uint)idn * EE;
            nva = ld4(item_w + o + e0);
            nvb = ld4(item_w + o + e1);
        }
        float ss = f4dot(va, va)  + f4dot(vb, vb);
        float d0 = f4dot(va, qa0) + f4dot(vb, qb0);
        float d1 = f4dot(va, qa1) + f4dot(vb, qb1);
        float d2 = f4dot(va, qa2) + f4dot(vb, qb2);
        float d3 = f4dot(va, qa3) + f4dot(vb, qb3);
        #pragma unroll
        for (int off = 1; off < 16; off <<= 1) {   // 4 rounds, within 16-lane group
            ss += __shfl_xor(ss, off, 64);
            d0 += __shfl_xor(d0, off, 64);
            d1 += __shfl_xor(d1, off, 64);
            d2 += __shfl_xor(d2, off, 64);
            d3 += __shfl_xor(d3, off, 64);
        }
        float n  = sqrtf(ss);
        float sc = (n > 1.f) ? 1.f / (n + 1e-7f) : 1.f;
        // maxnorm'd factors -> logits O(1): softmax without max subtraction
        float w0 = __expf(d0 * sc), w1 = __expf(d1 * sc);
        float w2 = __expf(d2 * sc), w3 = __expf(d3 * sc);
        if (i == 6 && wg >= 4) { w0 = 0.f; w1 = 0.f; w2 = 0.f; w3 = 0.f; }
        den0 += w0; den1 += w1; den2 += w2; den3 += w3;
        w0 *= sc; w1 *= sc; w2 *= sc; w3 *= sc;
        Sa0 = f4fma(va, w0, Sa0); Sb0 = f4fma(vb, w0, Sb0);
        Sa1 = f4fma(va, w1, Sa1); Sb1 = f4fma(vb, w1, Sb1);
        Sa2 = f4fma(va, w2, Sa2); Sb2 = f4fma(vb, w2, Sb2);
        Sa3 = f4fma(va, w3, Sa3); Sb3 = f4fma(vb, w3, Sb3);
        va = nva; vb = nvb;
    }

    // ---- combine the wave's 4 groups (same e-slice, disjoint rows) ----
    #pragma unroll
    for (int off = 16; off < 64; off <<= 1) {
        Sa0 = f4red(Sa0, off); Sb0 = f4red(Sb0, off);
        Sa1 = f4red(Sa1, off); Sb1 = f4red(Sb1, off);
        Sa2 = f4red(Sa2, off); Sb2 = f4red(Sb2, off);
        Sa3 = f4red(Sa3, off); Sb3 = f4red(Sb3, off);
        den0 += __shfl_xor(den0, off, 64);
        den1 += __shfl_xor(den1, off, 64);
        den2 += __shfl_xor(den2, off, 64);
        den3 += __shfl_xor(den3, off, 64);
    }
    if (g == 0) {
        st4(&s_part[wave][0][e0], Sa0); st4(&s_part[wave][0][e1], Sb0);
        st4(&s_part[wave][1][e0], Sa1); st4(&s_part[wave][1][e1], Sb1);
        st4(&s_part[wave][2][e0], Sa2); st4(&s_part[wave][2][e1], Sb2);
        st4(&s_part[wave][3][e0], Sa3); st4(&s_part[wave][3][e1], Sb3);
        if (hl == 0) {
            s_den[wave][0] = den0; s_den[wave][1] = den1;
            s_den[wave][2] = den2; s_den[wave][3] = den3;
        }
    }
    __syncthreads();

    // ---- final: cross-wave reduce + epilogue ----
    if (tid < EE) {
        int e = tid;
        float D0 = s_den[0][0] + s_den[1][0] + s_den[2][0] + s_den[3][0];
        float D1 = s_den[0][1] + s_den[1][1] + s_den[2][1] + s_den[3][1];
        float D2 = s_den[0][2] + s_den[1][2] + s_den[2][2] + s_den[3][2];
        float D3 = s_den[0][3] + s_den[1][3] + s_den[2][3] + s_den[3][3];
        float S0e = (s_part[0][0][e] + s_part[1][0][e] + s_part[2][0][e] + s_part[3][0][e]) / D0;
        float S1e = (s_part[0][1][e] + s_part[1][1][e] + s_part[2][1][e] + s_part[3][1][e]) / D1;
        float S2e = (s_part[0][2][e] + s_part[1][2][e] + s_part[2][2][e] + s_part[3][2][e]) / D2;
        float S3e = (s_part[0][3][e] + s_part[1][3][e] + s_part[2][3][e] + s_part[3][3][e]) / D3;
        float u = s_u[e], ip = s_ip[e], inn = s_in[e];
        float wae = ws[e], wie = ws[EE + e];
        float relp = ip  * wae * S0e + u * wie * S1e;
        float reln = inn * wae * S2e + u * wie * S3e;
        size_t base = (size_t)b * EE + e;
        out[3 * (size_t)BB * EE + base] = relp;
        out[4 * (size_t)BB * EE + base] = reln;
    }
}

extern "C" void kernel_launch(void* const* d_in, const int* in_sizes, int n_in,
                              void* d_out, int out_size, void* d_ws, size_t ws_size,
                              hipStream_t stream) {
    const int*   user_id   = (const int*)d_in[0];
    const int*   item_id_p = (const int*)d_in[1];
    const int*   item_id_n = (const int*)d_in[2];
    const int*   inter_id  = (const int*)d_in[3];
    const float* user_w    = (const float*)d_in[4];
    const float* item_w    = (const float*)d_in[5];
    const float* ua_key    = (const float*)d_in[6];
    const float* ua_val    = (const float*)d_in[7];
    const float* ia_key    = (const float*)d_in[8];
    const float* ia_val    = (const float*)d_in[9];
    float* out = (float*)d_out;
    float* ws  = (float*)d_ws;   // [0:128)=wsum_ua, [128:256)=wsum_ia

    wsum_kernel<<<2, 512, 0, stream>>>(ua_key, ua_val, ia_key, ia_val, ws);
    hlrm_main<<<BB, 256, 0, stream>>>(user_id, item_id_p, item_id_n, inter_id,
                                      user_w, item_w, ws, out);
}

// Round 4
// 50.450 us; speedup vs baseline: 4.1778x; 1.2601x over previous
//
#include <hip/hip_runtime.h>
#include <math.h>

#define BB 4096
#define MM 100
#define EE 128
#define RR 64

__device__ __forceinline__ float4 ld4(const float* p) {
    return *reinterpret_cast<const float4*>(p);
}
__device__ __forceinline__ void st4(float* p, float4 v) {
    *reinterpret_cast<float4*>(p) = v;
}
__device__ __forceinline__ float f4dot(float4 a, float4 b) {
    return a.x * b.x + a.y * b.y + a.z * b.z + a.w * b.w;
}
__device__ __forceinline__ float4 f4mul3(float4 a, float4 b, float4 c) {
    float4 r;
    r.x = a.x * b.x * c.x; r.y = a.y * b.y * c.y;
    r.z = a.z * b.z * c.z; r.w = a.w * b.w * c.w;
    return r;
}
__device__ __forceinline__ float4 f4fma(float4 v, float s, float4 acc) {
    acc.x += v.x * s; acc.y += v.y * s; acc.z += v.z * s; acc.w += v.w * s;
    return acc;
}
__device__ __forceinline__ float4 f4red(float4 a, int off) {
    a.x += __shfl_xor(a.x, off, 64); a.y += __shfl_xor(a.y, off, 64);
    a.z += __shfl_xor(a.z, off, 64); a.w += __shfl_xor(a.w, off, 64);
    return a;
}

// ---- DPP rotation all-reduce within a 16-lane row (pure VALU, no LDS pipe) ----
template<int CTRL>
__device__ __forceinline__ float dpp_add(float x) {
    int y = __builtin_amdgcn_update_dpp(0, __float_as_int(x), CTRL, 0xF, 0xF, true);
    return x + __int_as_float(y);
}
__device__ __forceinline__ float row16_allreduce(float x) {
    x = dpp_add<0x121>(x);   // row_ror:1
    x = dpp_add<0x122>(x);   // row_ror:2
    x = dpp_add<0x124>(x);   // row_ror:4
    x = dpp_add<0x128>(x);   // row_ror:8
    return x;
}

// ---- ws vectors: block 0 -> sum(ua_key*ua_val) over R; block 1 -> ia ----
__global__ __launch_bounds__(512)
void wsum_kernel(const float* __restrict__ ua_key, const float* __restrict__ ua_val,
                 const float* __restrict__ ia_key, const float* __restrict__ ia_val,
                 float* __restrict__ ws) {
    __shared__ float part[4][EE];
    const float* k = (blockIdx.x == 0) ? ua_key : ia_key;
    const float* v = (blockIdx.x == 0) ? ua_val : ia_val;
    int e = threadIdx.x & 127;
    int q = threadIdx.x >> 7;
    float s = 0.f;
    #pragma unroll
    for (int j = 0; j < 16; ++j) {
        int r = q * 16 + j;
        s += k[r * EE + e] * v[r * EE + e];
    }
    part[q][e] = s;
    __syncthreads();
    if (threadIdx.x < EE)
        ws[blockIdx.x * EE + e] = part[0][e] + part[1][e] + part[2][e] + part[3][e];
}

__global__ __launch_bounds__(256)
void hlrm_main(const int* __restrict__ user_id,
               const int* __restrict__ ip_id,
               const int* __restrict__ in_id,
               const int* __restrict__ inter_id,
               const float* __restrict__ user_w,
               const float* __restrict__ item_w,
               const float* __restrict__ ws,
               float* __restrict__ out) {
    __shared__ float s_u[EE], s_ip[EE], s_in[EE];
    __shared__ float s_part[4][4][EE];   // [wave][k][e]
    __shared__ float s_den[4][4];

    const int b    = blockIdx.x;
    const int tid  = threadIdx.x;
    const int lane = tid & 63;
    const int wave = tid >> 6;
    const int g    = lane >> 4;   // 16-lane group: one row per step
    const int hl   = lane & 15;   // owns elems e0..e0+3, e1..e1+3
    const int wg   = wave * 4 + g;
    const int e0   = hl * 4;
    const int e1   = 64 + hl * 4;

    // preload inter ids: lane j (<28) holds id for row (j>>2)*16 + wave*4 + (j&3)
    int idreg = 0;
    if (lane < 28) {
        int row = (lane >> 2) * 16 + wave * 4 + (lane & 3);
        if (row < MM) idreg = inter_id[b * MM + row];
    }
    // hoist all 7 id shuffles (independent ds_bpermutes)
    int ids[7];
    #pragma unroll
    for (int i = 0; i < 7; ++i) ids[i] = __shfl(idreg, i * 4 + g);

    // ---- depth-3 pipeline: issue tiles 0..2 now (overlap staging + barrier) ----
    float4 va0, vb0, va1, vb1, va2, vb2;
    {
        uint o = (uint)ids[0] * EE; va0 = ld4(item_w + o + e0); vb0 = ld4(item_w + o + e1);
        o = (uint)ids[1] * EE;      va1 = ld4(item_w + o + e0); vb1 = ld4(item_w + o + e1);
        o = (uint)ids[2] * EE;      va2 = ld4(item_w + o + e0); vb2 = ld4(item_w + o + e1);
    }

    // ---- stage u / ip / inn normalized into LDS (3 x 32-lane halves) ----
    if (wave == 0 || (wave == 1 && lane < 32)) {
        const int half32 = lane >> 5, l32 = lane & 31;
        const float* src; int id; float* dst;
        if (wave == 0 && half32 == 0) { id = user_id[b]; src = user_w; dst = s_u;  }
        else if (wave == 0)           { id = ip_id[b];   src = item_w; dst = s_ip; }
        else                          { id = in_id[b];   src = item_w; dst = s_in; }
        float4 v = ld4(src + (size_t)id * EE + l32 * 4);
        float ss = f4dot(v, v);
        #pragma unroll
        for (int off = 1; off < 32; off <<= 1) ss += __shfl_xor(ss, off, 64);
        float n  = sqrtf(ss);
        float sc = (n > 1.f) ? 1.f / (n + 1e-7f) : 1.f;
        float4 o; o.x = v.x * sc; o.y = v.y * sc; o.z = v.z * sc; o.w = v.w * sc;
        st4(dst + l32 * 4, o);
    }
    __syncthreads();

    // ---- per-lane q fragments (4 attention queries x 8 elems) ----
    float4 ua  = ld4(s_u + e0),  ub  = ld4(s_u + e1);
    float4 pa  = ld4(s_ip + e0), pb  = ld4(s_ip + e1);
    float4 ia  = ld4(s_in + e0), ib  = ld4(s_in + e1);
    float4 waa = ld4(ws + e0),   wab = ld4(ws + e1);
    float4 wia = ld4(ws + EE + e0), wib = ld4(ws + EE + e1);
    float4 qa0 = f4mul3(ua, pa, waa), qb0 = f4mul3(ub, pb, wab);
    float4 qa1 = f4mul3(ua, pa, wia), qb1 = f4mul3(ub, pb, wib);
    float4 qa2 = f4mul3(ua, ia, waa), qb2 = f4mul3(ub, ib, wab);
    float4 qa3 = f4mul3(ua, ia, wia), qb3 = f4mul3(ub, ib, wib);

    // emit u/ip/inn now so the stores overlap the main loop
    if (tid < EE) {
        size_t base = (size_t)b * EE + tid;
        out[0 * (size_t)BB * EE + base] = s_u[tid];
        out[1 * (size_t)BB * EE + base] = s_ip[tid];
        out[2 * (size_t)BB * EE + base] = s_in[tid];
    }

    float4 Sa0 = {0,0,0,0}, Sa1 = {0,0,0,0}, Sa2 = {0,0,0,0}, Sa3 = {0,0,0,0};
    float4 Sb0 = {0,0,0,0}, Sb1 = {0,0,0,0}, Sb2 = {0,0,0,0}, Sb3 = {0,0,0,0};
    float den0 = 0.f, den1 = 0.f, den2 = 0.f, den3 = 0.f;

#define LOADT(VA, VB, I) do {                                  \
        uint o = (uint)ids[I] * EE;                            \
        VA = ld4(item_w + o + e0);                             \
        VB = ld4(item_w + o + e1);                             \
    } while (0)

#define STEP(VA, VB, I) do {                                                   \
        float ss = f4dot(VA, VA)  + f4dot(VB, VB);                             \
        float d0 = f4dot(VA, qa0) + f4dot(VB, qb0);                            \
        float d1 = f4dot(VA, qa1) + f4dot(VB, qb1);                            \
        float d2 = f4dot(VA, qa2) + f4dot(VB, qb2);                            \
        float d3 = f4dot(VA, qa3) + f4dot(VB, qb3);                            \
        ss = row16_allreduce(ss);                                              \
        d0 = row16_allreduce(d0); d1 = row16_allreduce(d1);                    \
        d2 = row16_allreduce(d2); d3 = row16_allreduce(d3);                    \
        float sc = (ss > 1.f) ? __builtin_amdgcn_rsqf(ss) : 1.f;               \
        float w0 = __expf(d0 * sc), w1 = __expf(d1 * sc);                      \
        float w2 = __expf(d2 * sc), w3 = __expf(d3 * sc);                      \
        if ((I) == 6 && wg >= 4) { w0 = 0.f; w1 = 0.f; w2 = 0.f; w3 = 0.f; }   \
        den0 += w0; den1 += w1; den2 += w2; den3 += w3;                        \
        w0 *= sc; w1 *= sc; w2 *= sc; w3 *= sc;                                \
        Sa0 = f4fma(VA, w0, Sa0); Sb0 = f4fma(VB, w0, Sb0);                    \
        Sa1 = f4fma(VA, w1, Sa1); Sb1 = f4fma(VB, w1, Sb1);                    \
        Sa2 = f4fma(VA, w2, Sa2); Sb2 = f4fma(VB, w2, Sb2);                    \
        Sa3 = f4fma(VA, w3, Sa3); Sb3 = f4fma(VB, w3, Sb3);                    \
    } while (0)

    // ---- fully unrolled 7-step main loop, 3 tiles in flight ----
    STEP(va0, vb0, 0); LOADT(va0, vb0, 3);
    STEP(va1, vb1, 1); LOADT(va1, vb1, 4);
    STEP(va2, vb2, 2); LOADT(va2, vb2, 5);
    STEP(va0, vb0, 3); LOADT(va0, vb0, 6);
    STEP(va1, vb1, 4);
    STEP(va2, vb2, 5);
    STEP(va0, vb0, 6);

#undef STEP
#undef LOADT

    // ---- combine the wave's 4 groups (same e-slice, disjoint rows) ----
    #pragma unroll
    for (int off = 16; off < 64; off <<= 1) {
        Sa0 = f4red(Sa0, off); Sb0 = f4red(Sb0, off);
        Sa1 = f4red(Sa1, off); Sb1 = f4red(Sb1, off);
        Sa2 = f4red(Sa2, off); Sb2 = f4red(Sb2, off);
        Sa3 = f4red(Sa3, off); Sb3 = f4red(Sb3, off);
        den0 += __shfl_xor(den0, off, 64);
        den1 += __shfl_xor(den1, off, 64);
        den2 += __shfl_xor(den2, off, 64);
        den3 += __shfl_xor(den3, off, 64);
    }
    if (g == 0) {
        st4(&s_part[wave][0][e0], Sa0); st4(&s_part[wave][0][e1], Sb0);
        st4(&s_part[wave][1][e0], Sa1); st4(&s_part[wave][1][e1], Sb1);
        st4(&s_part[wave][2][e0], Sa2); st4(&s_part[wave][2][e1], Sb2);
        st4(&s_part[wave][3][e0], Sa3); st4(&s_part[wave][3][e1], Sb3);
        if (hl == 0) {
            s_den[wave][0] = den0; s_den[wave][1] = den1;
            s_den[wave][2] = den2; s_den[wave][3] = den3;
        }
    }
    __syncthreads();

    // ---- final: cross-wave reduce + epilogue ----
    if (tid < EE) {
        int e = tid;
        float D0 = s_den[0][0] + s_den[1][0] + s_den[2][0] + s_den[3][0];
        float D1 = s_den[0][1] + s_den[1][1] + s_den[2][1] + s_den[3][1];
        float D2 = s_den[0][2] + s_den[1][2] + s_den[2][2] + s_den[3][2];
        float D3 = s_den[0][3] + s_den[1][3] + s_den[2][3] + s_den[3][3];
        float S0e = (s_part[0][0][e] + s_part[1][0][e] + s_part[2][0][e] + s_part[3][0][e]) / D0;
        float S1e = (s_part[0][1][e] + s_part[1][1][e] + s_part[2][1][e] + s_part[3][1][e]) / D1;
        float S2e = (s_part[0][2][e] + s_part[1][2][e] + s_part[2][2][e] + s_part[3][2][e]) / D2;
        float S3e = (s_part[0][3][e] + s_part[1][3][e] + s_part[2][3][e] + s_part[3][3][e]) / D3;
        float u = s_u[e], ip = s_ip[e], inn = s_in[e];
        float wae = ws[e], wie = ws[EE + e];
        float relp = ip  * wae * S0e + u * wie * S1e;
        float reln = inn * wae * S2e + u * wie * S3e;
        size_t base = (size_t)b * EE + e;
        out[3 * (size_t)BB * EE + base] = relp;
        out[4 * (size_t)BB * EE + base] = reln;
    }
}

extern "C" void kernel_launch(void* const* d_in, const int* in_sizes, int n_in,
                              void* d_out, int out_size, void* d_ws, size_t ws_size,
                              hipStream_t stream) {
    const int*   user_id   = (const int*)d_in[0];
    const int*   item_id_p = (const int*)d_in[1];
    const int*   item_id_n = (const int*)d_in[2];
    const int*   inter_id  = (const int*)d_in[3];
    const float* user_w    = (const float*)d_in[4];
    const float* item_w    = (const float*)d_in[5];
    const float* ua_key    = (const float*)d_in[6];
    const float* ua_val    = (const float*)d_in[7];
    const float* ia_key    = (const float*)d_in[8];
    const float* ia_val    = (const float*)d_in[9];
    float* out = (float*)d_out;
    float* ws  = (float*)d_ws;   // [0:128)=wsum_ua, [128:256)=wsum_ia

    wsum_kernel<<<2, 512, 0, stream>>>(ua_key, ua_val, ia_key, ia_val, ws);
    hlrm_main<<<BB, 256, 0, stream>>>(user_id, item_id_p, item_id_n, inter_id,
                                      user_w, item_w, ws, out);
}

// Round 5
// 50.394 us; speedup vs baseline: 4.1824x; 1.0011x over previous
//
#include <hip/hip_runtime.h>
#include <math.h>

#define BB 4096
#define MM 100
#define EE 128
#define RR 64

__device__ __forceinline__ float4 ld4(const float* p) {
    return *reinterpret_cast<const float4*>(p);
}
__device__ __forceinline__ void st4(float* p, float4 v) {
    *reinterpret_cast<float4*>(p) = v;
}
__device__ __forceinline__ float f4dot(float4 a, float4 b) {
    return a.x * b.x + a.y * b.y + a.z * b.z + a.w * b.w;
}
__device__ __forceinline__ float4 f4mul3(float4 a, float4 b, float4 c) {
    float4 r;
    r.x = a.x * b.x * c.x; r.y = a.y * b.y * c.y;
    r.z = a.z * b.z * c.z; r.w = a.w * b.w * c.w;
    return r;
}
__device__ __forceinline__ float4 f4scale(float4 a, float s) {
    float4 r; r.x = a.x * s; r.y = a.y * s; r.z = a.z * s; r.w = a.w * s;
    return r;
}
__device__ __forceinline__ float4 f4fma(float4 v, float s, float4 acc) {
    acc.x += v.x * s; acc.y += v.y * s; acc.z += v.z * s; acc.w += v.w * s;
    return acc;
}
__device__ __forceinline__ float4 f4red(float4 a, int off) {
    a.x += __shfl_xor(a.x, off, 64); a.y += __shfl_xor(a.y, off, 64);
    a.z += __shfl_xor(a.z, off, 64); a.w += __shfl_xor(a.w, off, 64);
    return a;
}
// rel = x1*w1*(S1*i1) + x2*w2*(S2*i2), elementwise
__device__ __forceinline__ float4 relcomb(float4 x1, float4 w1, float4 S1v, float i1,
                                          float4 x2, float4 w2, float4 S2v, float i2) {
    float4 r;
    r.x = x1.x * w1.x * (S1v.x * i1) + x2.x * w2.x * (S2v.x * i2);
    r.y = x1.y * w1.y * (S1v.y * i1) + x2.y * w2.y * (S2v.y * i2);
    r.z = x1.z * w1.z * (S1v.z * i1) + x2.z * w2.z * (S2v.z * i2);
    r.w = x1.w * w1.w * (S1v.w * i1) + x2.w * w2.w * (S2v.w * i2);
    return r;
}

// ---- DPP rotation all-reduce within a 16-lane row (pure VALU, no LDS pipe) ----
template<int CTRL>
__device__ __forceinline__ float dpp_add(float x) {
    int y = __builtin_amdgcn_update_dpp(0, __float_as_int(x), CTRL, 0xF, 0xF, true);
    return x + __int_as_float(y);
}
__device__ __forceinline__ float row16_allreduce(float x) {
    x = dpp_add<0x121>(x);   // row_ror:1
    x = dpp_add<0x122>(x);   // row_ror:2
    x = dpp_add<0x124>(x);   // row_ror:4
    x = dpp_add<0x128>(x);   // row_ror:8
    return x;
}

// ---- ws vectors: block 0 -> sum(ua_key*ua_val) over R; block 1 -> ia ----
__global__ __launch_bounds__(512)
void wsum_kernel(const float* __restrict__ ua_key, const float* __restrict__ ua_val,
                 const float* __restrict__ ia_key, const float* __restrict__ ia_val,
                 float* __restrict__ ws) {
    __shared__ float part[4][EE];
    const float* k = (blockIdx.x == 0) ? ua_key : ia_key;
    const float* v = (blockIdx.x == 0) ? ua_val : ia_val;
    int e = threadIdx.x & 127;
    int q = threadIdx.x >> 7;
    float s = 0.f;
    #pragma unroll
    for (int j = 0; j < 16; ++j) {
        int r = q * 16 + j;
        s += k[r * EE + e] * v[r * EE + e];
    }
    part[q][e] = s;
    __syncthreads();
    if (threadIdx.x < EE)
        ws[blockIdx.x * EE + e] = part[0][e] + part[1][e] + part[2][e] + part[3][e];
}

// One wave per b: 4 groups of 16 lanes, group g handles rows 4s+g, s=0..24.
__global__ __launch_bounds__(256)
void hlrm_main(const int* __restrict__ user_id,
               const int* __restrict__ ip_id,
               const int* __restrict__ in_id,
               const int* __restrict__ inter_id,
               const float* __restrict__ user_w,
               const float* __restrict__ item_w,
               const float* __restrict__ ws,
               float* __restrict__ out) {
    __shared__ int s_ids[4][MM];   // 1600 B, one 400 B slice per wave

    const int tid  = threadIdx.x;
    const int lane = tid & 63;
    const int wave = tid >> 6;
    const int b    = blockIdx.x * 4 + wave;
    const int g    = lane >> 4;
    const int hl   = lane & 15;
    const int e0   = hl * 4;
    const int e1   = 64 + hl * 4;
    int* sw = s_ids[wave];

    // ---- stage this b's 100 inter ids into the wave's LDS slice ----
    if (lane < 50)
        *reinterpret_cast<int2*>(sw + 2 * lane) =
            *reinterpret_cast<const int2*>(inter_id + b * MM + 2 * lane);

    // entity ids (broadcast loads) + rows + ws (independent vmem chain)
    int uid = user_id[b], pid = ip_id[b], nid = in_id[b];
    float4 ru_a = ld4(user_w + (uint)uid * EE + e0);
    float4 ru_b = ld4(user_w + (uint)uid * EE + e1);
    float4 rp_a = ld4(item_w + (uint)pid * EE + e0);
    float4 rp_b = ld4(item_w + (uint)pid * EE + e1);
    float4 rn_a = ld4(item_w + (uint)nid * EE + e0);
    float4 rn_b = ld4(item_w + (uint)nid * EE + e1);
    float4 waa = ld4(ws + e0),      wab = ld4(ws + e1);
    float4 wia = ld4(ws + EE + e0), wib = ld4(ws + EE + e1);

    // ---- sids for steps 0..4, issue 10 tile loads (depth-5 pipeline) ----
    int sid0 = sw[g], sid1 = sw[4 + g], sid2 = sw[8 + g],
        sid3 = sw[12 + g], sid4 = sw[16 + g];
    float4 va0, vb0, va1, vb1, va2, vb2, va3, vb3, va4, vb4;
#define LOADT(J) do {                                   \
        uint o = (uint)sid##J * EE;                     \
        va##J = ld4(item_w + o + e0);                   \
        vb##J = ld4(item_w + o + e1);                   \
    } while (0)
    LOADT(0); LOADT(1); LOADT(2); LOADT(3); LOADT(4);
    // sids for steps 5..9 (one body ahead)
    sid0 = sw[20 + g]; sid1 = sw[24 + g]; sid2 = sw[28 + g];
    sid3 = sw[32 + g]; sid4 = sw[36 + g];

    // ---- norms/scales for u, ip, inn (redundant per 16-lane group) ----
    float ssu = f4dot(ru_a, ru_a) + f4dot(ru_b, ru_b);
    float ssp = f4dot(rp_a, rp_a) + f4dot(rp_b, rp_b);
    float ssn = f4dot(rn_a, rn_a) + f4dot(rn_b, rn_b);
    ssu = row16_allreduce(ssu);
    ssp = row16_allreduce(ssp);
    ssn = row16_allreduce(ssn);
    float scu = (ssu > 1.f) ? __builtin_amdgcn_rsqf(ssu) : 1.f;
    float scp = (ssp > 1.f) ? __builtin_amdgcn_rsqf(ssp) : 1.f;
    float scn = (ssn > 1.f) ? __builtin_amdgcn_rsqf(ssn) : 1.f;

    // ---- q fragments (4 queries x 8 elems per lane) ----
    float cup = scu * scp, cun = scu * scn;
    float4 qa0 = f4scale(f4mul3(ru_a, rp_a, waa), cup);
    float4 qb0 = f4scale(f4mul3(ru_b, rp_b, wab), cup);
    float4 qa1 = f4scale(f4mul3(ru_a, rp_a, wia), cup);
    float4 qb1 = f4scale(f4mul3(ru_b, rp_b, wib), cup);
    float4 qa2 = f4scale(f4mul3(ru_a, rn_a, waa), cun);
    float4 qb2 = f4scale(f4mul3(ru_b, rn_b, wab), cun);
    float4 qa3 = f4scale(f4mul3(ru_a, rn_a, wia), cun);
    float4 qb3 = f4scale(f4mul3(ru_b, rn_b, wib), cun);

    float4 Sa0 = {0,0,0,0}, Sa1 = {0,0,0,0}, Sa2 = {0,0,0,0}, Sa3 = {0,0,0,0};
    float4 Sb0 = {0,0,0,0}, Sb1 = {0,0,0,0}, Sb2 = {0,0,0,0}, Sb3 = {0,0,0,0};
    float den0 = 0.f, den1 = 0.f, den2 = 0.f, den3 = 0.f;

#define STEP(J) do {                                                        \
        float ss = f4dot(va##J, va##J) + f4dot(vb##J, vb##J);               \
        float d0 = f4dot(va##J, qa0) + f4dot(vb##J, qb0);                   \
        float d1 = f4dot(va##J, qa1) + f4dot(vb##J, qb1);                   \
        float d2 = f4dot(va##J, qa2) + f4dot(vb##J, qb2);                   \
        float d3 = f4dot(va##J, qa3) + f4dot(vb##J, qb3);                   \
        ss = row16_allreduce(ss);                                           \
        d0 = row16_allreduce(d0); d1 = row16_allreduce(d1);                 \
        d2 = row16_allreduce(d2); d3 = row16_allreduce(d3);                 \
        float sc = (ss > 1.f) ? __builtin_amdgcn_rsqf(ss) : 1.f;            \
        float w0 = __expf(d0 * sc), w1 = __expf(d1 * sc);                   \
        float w2 = __expf(d2 * sc), w3 = __expf(d3 * sc);                   \
        den0 += w0; den1 += w1; den2 += w2; den3 += w3;                     \
        w0 *= sc; w1 *= sc; w2 *= sc; w3 *= sc;                             \
        Sa0 = f4fma(va##J, w0, Sa0); Sb0 = f4fma(vb##J, w0, Sb0);           \
        Sa1 = f4fma(va##J, w1, Sa1); Sb1 = f4fma(vb##J, w1, Sb1);           \
        Sa2 = f4fma(va##J, w2, Sa2); Sb2 = f4fma(vb##J, w2, Sb2);           \
        Sa3 = f4fma(va##J, w3, Sa3); Sb3 = f4fma(vb##J, w3, Sb3);           \
    } while (0)

    // ---- 25 steps: 4 bodies of 5 (with loads for s+5) + 5-step tail ----
    #pragma unroll 1
    for (int it = 0; it < 4; ++it) {
        STEP(0); LOADT(0);
        STEP(1); LOADT(1);
        STEP(2); LOADT(2);
        STEP(3); LOADT(3);
        STEP(4); LOADT(4);
        if (it < 3) {   // sids for the NEXT body's loads (steps it*5+10 ..)
            int o = (it * 5 + 10) * 4 + g;
            sid0 = sw[o];      sid1 = sw[o + 4];  sid2 = sw[o + 8];
            sid3 = sw[o + 12]; sid4 = sw[o + 16];
        }
    }
    STEP(0); STEP(1); STEP(2); STEP(3); STEP(4);   // steps 20..24
#undef STEP
#undef LOADT

    // ---- cross-group combine (off 16, 32): disjoint row sets, same e-slice ----
    #pragma unroll
    for (int off = 16; off < 64; off <<= 1) {
        Sa0 = f4red(Sa0, off); Sb0 = f4red(Sb0, off);
        Sa1 = f4red(Sa1, off); Sb1 = f4red(Sb1, off);
        Sa2 = f4red(Sa2, off); Sb2 = f4red(Sb2, off);
        Sa3 = f4red(Sa3, off); Sb3 = f4red(Sb3, off);
        den0 += __shfl_xor(den0, off, 64);
        den1 += __shfl_xor(den1, off, 64);
        den2 += __shfl_xor(den2, off, 64);
        den3 += __shfl_xor(den3, off, 64);
    }
    float iD0 = 1.f / den0, iD1 = 1.f / den1, iD2 = 1.f / den2, iD3 = 1.f / den3;

    // ---- epilogue: reload entity rows (L2-hot), scale, emit all 5 outputs ----
    float4 u_a = f4scale(ld4(user_w + (uint)uid * EE + e0), scu);
    float4 u_b = f4scale(ld4(user_w + (uint)uid * EE + e1), scu);
    float4 p_a = f4scale(ld4(item_w + (uint)pid * EE + e0), scp);
    float4 p_b = f4scale(ld4(item_w + (uint)pid * EE + e1), scp);
    float4 n_a = f4scale(ld4(item_w + (uint)nid * EE + e0), scn);
    float4 n_b = f4scale(ld4(item_w + (uint)nid * EE + e1), scn);
    float4 w0a = ld4(ws + e0),      w0b = ld4(ws + e1);
    float4 w1a = ld4(ws + EE + e0), w1b = ld4(ws + EE + e1);

    size_t base = (size_t)b * EE;
    const size_t P = (size_t)BB * EE;
    if (g == 0) {
        float4 ra = relcomb(p_a, w0a, Sa0, iD0, u_a, w1a, Sa1, iD1);
        float4 rb = relcomb(p_b, w0b, Sb0, iD0, u_b, w1b, Sb1, iD1);
        st4(out + 3 * P + base + e0, ra);
        st4(out + 3 * P + base + e1, rb);
    } else if (g == 1) {
        float4 ra = relcomb(n_a, w0a, Sa2, iD2, u_a, w1a, Sa3, iD3);
        float4 rb = relcomb(n_b, w0b, Sb2, iD2, u_b, w1b, Sb3, iD3);
        st4(out + 4 * P + base + e0, ra);
        st4(out + 4 * P + base + e1, rb);
    } else if (g == 2) {
        st4(out + 0 * P + base + e0, u_a);
        st4(out + 0 * P + base + e1, u_b);
        st4(out + 1 * P + base + e0, p_a);
        st4(out + 1 * P + base + e1, p_b);
    } else {
        st4(out + 2 * P + base + e0, n_a);
        st4(out + 2 * P + base + e1, n_b);
    }
}

extern "C" void kernel_launch(void* const* d_in, const int* in_sizes, int n_in,
                              void* d_out, int out_size, void* d_ws, size_t ws_size,
                              hipStream_t stream) {
    const int*   user_id   = (const int*)d_in[0];
    const int*   item_id_p = (const int*)d_in[1];
    const int*   item_id_n = (const int*)d_in[2];
    const int*   inter_id  = (const int*)d_in[3];
    const float* user_w    = (const float*)d_in[4];
    const float* item_w    = (const float*)d_in[5];
    const float* ua_key    = (const float*)d_in[6];
    const float* ua_val    = (const float*)d_in[7];
    const float* ia_key    = (const float*)d_in[8];
    const float* ia_val    = (const float*)d_in[9];
    float* out = (float*)d_out;
    float* ws  = (float*)d_ws;   // [0:128)=wsum_ua, [128:256)=wsum_ia

    wsum_kernel<<<2, 512, 0, stream>>>(ua_key, ua_val, ia_key, ia_val, ws);
    hlrm_main<<<BB / 4, 256, 0, stream>>>(user_id, item_id_p, item_id_n, inter_id,
                                          user_w, item_w, ws, out);
}